// Round 12
// baseline (577.061 us; speedup 1.0000x reference)
//
#include <hip/hip_runtime.h>

__device__ __forceinline__ int rfl(int v) { return __builtin_amdgcn_readfirstlane(v); }

__device__ __forceinline__ int lower_bound_dev(const int* __restrict__ a, int n, int v) {
  int lo = 0, hi = n;
  while (lo < hi) { int mid = (lo + hi) >> 1; if (a[mid] < v) lo = mid + 1; else hi = mid; }
  return lo;
}

// ---------------- fast zero ----------------
__global__ void zero_kernel(int4* __restrict__ p, int n4) {
  int i = blockIdx.x * 256 + threadIdx.x;
  if (i < n4) p[i] = make_int4(0, 0, 0, 0);
}

// ---------------- CSR build ----------------
__global__ void count_pack_kernel(const int* __restrict__ dst, const int* __restrict__ src,
                                  const int* __restrict__ gt, int* __restrict__ counts,
                                  int* __restrict__ epack0, int E) {
  int e = blockIdx.x * 256 + threadIdx.x;
  if (e < E) {
    atomicAdd(&counts[dst[e]], 1);
    epack0[e] = (gt[e] << 20) | src[e];
  }
}

__global__ __launch_bounds__(256) void scan_phase1(const int* __restrict__ counts,
                                                   int* __restrict__ row_ptr,
                                                   int* __restrict__ blocksums, int n) {
  int tid = threadIdx.x;
  int i0 = blockIdx.x * 1024 + tid * 4;
  int4 c = make_int4(0, 0, 0, 0);
  if (i0 + 3 < n) {
    c = *(const int4*)(counts + i0);
  } else {
    if (i0 + 0 < n) c.x = counts[i0 + 0];
    if (i0 + 1 < n) c.y = counts[i0 + 1];
    if (i0 + 2 < n) c.z = counts[i0 + 2];
    if (i0 + 3 < n) c.w = counts[i0 + 3];
  }
  int s = c.x + c.y + c.z + c.w;
  int lane = tid & 63, wave = tid >> 6;
  int v = s;
  for (int o = 1; o < 64; o <<= 1) { int u = __shfl_up(v, o); if (lane >= o) v += u; }
  __shared__ int wsum[4];
  if (lane == 63) wsum[wave] = v;
  __syncthreads();
  int woff = 0;
  for (int w = 0; w < wave; w++) woff += wsum[w];
  int excl = woff + (v - s);
  if (tid == 255) blocksums[blockIdx.x] = woff + v;
  int p0 = excl, p1 = p0 + c.x, p2 = p1 + c.y, p3 = p2 + c.z;
  if (i0 + 3 < n) {
    *(int4*)(row_ptr + i0) = make_int4(p0, p1, p2, p3);
  } else {
    if (i0 + 0 < n) row_ptr[i0 + 0] = p0;
    if (i0 + 1 < n) row_ptr[i0 + 1] = p1;
    if (i0 + 2 < n) row_ptr[i0 + 2] = p2;
    if (i0 + 3 < n) row_ptr[i0 + 3] = p3;
  }
}

__global__ __launch_bounds__(64) void scan_phase2(int* __restrict__ blocksums, int nb) {
  int carry = 0;
  for (int base = 0; base < nb; base += 64) {
    int i = base + (int)threadIdx.x;
    int v = (i < nb) ? blocksums[i] : 0;
    int inc = v;
    for (int o = 1; o < 64; o <<= 1) { int u = __shfl_up(inc, o); if ((int)threadIdx.x >= o) inc += u; }
    if (i < nb) blocksums[i] = carry + inc - v;
    carry += __shfl(inc, 63);
  }
}

__global__ __launch_bounds__(256) void scan_phase3(int* __restrict__ row_ptr,
                                                   const int* __restrict__ blocksums,
                                                   int* __restrict__ nextp, int n, int E) {
  int i = blockIdx.x * 256 + threadIdx.x;
  if (i < n) {
    int v = row_ptr[i] + blocksums[i >> 10];
    row_ptr[i] = v;
    nextp[i] = v;
  }
  if (i == 0) row_ptr[n] = E;
}

// XCD-binned scatter (R9 config — measured 40us): 8 dst-range phases.
#define SP_EDGES_PER_BLOCK 2048
__global__ __launch_bounds__(256) void scatter_perm_binned(const int* __restrict__ dst,
                                                           int* __restrict__ nextp,
                                                           int* __restrict__ perm,
                                                           int E, int n_nodes) {
  int phase = blockIdx.x & 7;
  int chunk = blockIdx.x >> 3;
  int lo = (int)(((long long)phase * n_nodes) >> 3);
  int hi = (int)(((long long)(phase + 1) * n_nodes) >> 3);
  int base = chunk * SP_EDGES_PER_BLOCK + threadIdx.x * 8;
#pragma unroll
  for (int half = 0; half < 2; half++) {
    int b = base + half * 4;
    if (b >= E) break;
    int4 d;
    if (b + 3 < E) {
      d = *(const int4*)(dst + b);
    } else {
      d.x = dst[b];
      d.y = (b + 1 < E) ? dst[b + 1] : -1;
      d.z = (b + 2 < E) ? dst[b + 2] : -1;
      d.w = (b + 3 < E) ? dst[b + 3] : -1;
    }
    if (d.x >= lo && d.x < hi) { int p = atomicAdd(&nextp[d.x], 1); perm[p] = b + 0; }
    if (d.y >= lo && d.y < hi) { int p = atomicAdd(&nextp[d.y], 1); perm[p] = b + 1; }
    if (d.z >= lo && d.z < hi) { int p = atomicAdd(&nextp[d.z], 1); perm[p] = b + 2; }
    if (d.w >= lo && d.w < hi) { int p = atomicAdd(&nextp[d.w], 1); perm[p] = b + 3; }
  }
}

// pass B (R9 config): CSR-order gather; all writes sequential/coalesced.
__global__ void gather_build(const int* __restrict__ perm, const int* __restrict__ epack0,
                             const float* __restrict__ edge_attr,
                             int* __restrict__ epack, float* __restrict__ eap, int E) {
  int idx = blockIdx.x * 256 + threadIdx.x;
  if (idx < E) {
    int e = perm[idx];
    epack[idx] = epack0[e];
    const float4* s = (const float4*)(edge_attr + (size_t)e * 8);
    float4 a0 = s[0], a1 = s[1];
    float4* d = (float4*)(eap + (size_t)idx * 8);
    d[0] = a0; d[1] = a1;
  }
}

// ---------------- gate-embedding @ W3 table ----------------
__global__ void gew_kernel(const float* __restrict__ gate_emb, const float* __restrict__ W_msg,
                           float* __restrict__ geW, int nrows) {
  int tid = threadIdx.x;
  int lane = tid & 63;
  int row = blockIdx.x * 4 + (tid >> 6);
  if (row >= nrows) return;
  int l = row / 20, t = row % 20;
  const float* ge = gate_emb + ((size_t)l * 20 + t) * 16;
  const float* W3 = W_msg + (size_t)l * 88 * 64 + 72 * 64;
  float acc = 0.f;
#pragma unroll
  for (int k = 0; k < 16; k++) acc = fmaf(ge[k], W3[(size_t)k * 64 + lane], acc);
  geW[(size_t)row * 64 + lane] = acc;
}

// ---------------- node embed ----------------
__global__ __launch_bounds__(256) void embed_kernel(const float* __restrict__ x,
                                                    const float* __restrict__ W,
                                                    const float* __restrict__ b,
                                                    const float* __restrict__ gamma,
                                                    const float* __restrict__ beta,
                                                    float* __restrict__ h, int n_nodes) {
  __shared__ float Ws[16 * 64];
  int tid = threadIdx.x;
  for (int i = tid; i < 16 * 64; i += 256) Ws[i] = W[i];
  __syncthreads();
  int lane = tid & 63;
  int n = blockIdx.x * 4 + (tid >> 6);
  if (n >= n_nodes) return;
  const float* xr = x + (size_t)n * 16;
  float acc = b[lane];
#pragma unroll
  for (int k = 0; k < 16; k++) acc = fmaf(xr[k], Ws[k * 64 + lane], acc);
  acc = fmaxf(acc, 0.f);
  float s = acc;
  for (int o = 32; o; o >>= 1) s += __shfl_xor(s, o);
  float mu = s * (1.f / 64.f);
  float d = acc - mu;
  float v = d * d;
  for (int o = 32; o; o >>= 1) v += __shfl_xor(v, o);
  float r = rsqrtf(v * (1.f / 64.f) + 1e-5f);
  h[(size_t)n * 64 + lane] = d * r * gamma[lane] + beta[lane];
}

// ---- tiled GEMM: C = A @ W (layer-0 hW); swizzled A tile, W from L1 ----
__global__ __launch_bounds__(256) void nodelin_kernel(const float* __restrict__ A,
                                                      const float* __restrict__ W,
                                                      float* __restrict__ C, int n_nodes) {
  __shared__ float As[64 * 64];
  int tid = threadIdx.x;
  int n0 = blockIdx.x * 64;
#pragma unroll
  for (int i = 0; i < 4; i++) {
    int flat = (tid + i * 256) * 4;
    int r = flat >> 6, k = flat & 63;
    float4 f = make_float4(0.f, 0.f, 0.f, 0.f);
    int n = n0 + r;
    if (n < n_nodes) f = *(const float4*)(A + (size_t)n * 64 + k);
    int rp = r ^ (((k >> 2) & 7) << 2);
    As[(k + 0) * 64 + rp] = f.x;
    As[(k + 1) * 64 + rp] = f.y;
    As[(k + 2) * 64 + rp] = f.z;
    As[(k + 3) * 64 + rp] = f.w;
  }
  __syncthreads();
  int tx = tid & 15, ty = tid >> 4;
  float acc[4][4] = {{0.f}};
  const float4* WV = (const float4*)W;
#pragma unroll 4
  for (int k = 0; k < 64; k++) {
    float4 a = *(const float4*)&As[k * 64 + ((ty * 4) ^ (((k >> 2) & 7) << 2))];
    float4 bb = WV[k * 16 + tx];
    float av[4] = {a.x, a.y, a.z, a.w};
    float bv[4] = {bb.x, bb.y, bb.z, bb.w};
#pragma unroll
    for (int i = 0; i < 4; i++)
#pragma unroll
      for (int j = 0; j < 4; j++) acc[i][j] = fmaf(av[i], bv[j], acc[i][j]);
  }
#pragma unroll
  for (int i = 0; i < 4; i++) {
    int n = n0 + ty * 4 + i;
    if (n < n_nodes) {
      float4 o = make_float4(acc[i][0], acc[i][1], acc[i][2], acc[i][3]);
      *(float4*)&C[(size_t)n * 64 + tx * 4] = o;
    }
  }
}

// -------- edge stage: HALF-WAVE SPLIT — each wave = 2 nodes, lanes 0-31 / 32-63.
// Each lane covers 2 h-dims (float2). One hW load instruction fetches 2 random rows
// (one per half) -> ILP-4 unroll = 8 rows in flight per wave, enforced by the memory
// system (compiler cannot register-serialize it away like thread-level ILP).
__global__ __launch_bounds__(256, 4) void edge_kernel(const float* __restrict__ hW,
                                                      const int* __restrict__ epack,
                                                      const float* __restrict__ eap,
                                                      const int* __restrict__ row_ptr,
                                                      const float* __restrict__ W_msg_l,
                                                      const float* __restrict__ b_msg_l,
                                                      const float* __restrict__ geW_l,
                                                      float* __restrict__ agg, int n_nodes) {
  int tid = threadIdx.x;
  int lane = tid & 63;
  int wave = tid >> 6;
  int sub = lane & 31;      // h-dim pair index
  int half = lane >> 5;     // which node of the pair
  int n = blockIdx.x * 8 + wave * 2 + half;
  if (n >= n_nodes) return;
  int d0 = sub * 2;
  float2 w2[8];
#pragma unroll
  for (int k = 0; k < 8; k++) w2[k] = *(const float2*)&W_msg_l[(size_t)(64 + k) * 64 + d0];
  float2 bm = *(const float2*)&b_msg_l[d0];
  int beg = row_ptr[n];
  int end = row_ptr[n + 1];
  float2 acc0 = make_float2(0.f, 0.f), acc1 = make_float2(0.f, 0.f);
  float2 acc2 = make_float2(0.f, 0.f), acc3 = make_float2(0.f, 0.f);
  int idx = beg;
  for (; idx + 4 <= end; idx += 4) {
    int p0 = epack[idx + 0];
    int p1 = epack[idx + 1];
    int p2 = epack[idx + 2];
    int p3 = epack[idx + 3];
    int s0 = p0 & 0xFFFFF, t0 = p0 >> 20;
    int s1 = p1 & 0xFFFFF, t1 = p1 >> 20;
    int s2 = p2 & 0xFFFFF, t2 = p2 >> 20;
    int s3 = p3 & 0xFFFFF, t3 = p3 >> 20;
    float2 g0 = *(const float2*)&hW[(size_t)s0 * 64 + d0];
    float2 g1 = *(const float2*)&hW[(size_t)s1 * 64 + d0];
    float2 g2 = *(const float2*)&hW[(size_t)s2 * 64 + d0];
    float2 g3 = *(const float2*)&hW[(size_t)s3 * 64 + d0];
    float2 e0 = *(const float2*)&geW_l[t0 * 64 + d0];
    float2 e1 = *(const float2*)&geW_l[t1 * 64 + d0];
    float2 e2 = *(const float2*)&geW_l[t2 * 64 + d0];
    float2 e3 = *(const float2*)&geW_l[t3 * 64 + d0];
    const float4* ep = (const float4*)(eap + (size_t)idx * 8);
    float4 a00 = ep[0], a01 = ep[1], a10 = ep[2], a11 = ep[3];
    float4 a20 = ep[4], a21 = ep[5], a30 = ep[6], a31 = ep[7];
    float2 v0, v1, v2, v3;
    v0.x = g0.x + e0.x + bm.x; v0.y = g0.y + e0.y + bm.y;
    v0.x = fmaf(a00.x, w2[0].x, v0.x); v0.y = fmaf(a00.x, w2[0].y, v0.y);
    v0.x = fmaf(a00.y, w2[1].x, v0.x); v0.y = fmaf(a00.y, w2[1].y, v0.y);
    v0.x = fmaf(a00.z, w2[2].x, v0.x); v0.y = fmaf(a00.z, w2[2].y, v0.y);
    v0.x = fmaf(a00.w, w2[3].x, v0.x); v0.y = fmaf(a00.w, w2[3].y, v0.y);
    v0.x = fmaf(a01.x, w2[4].x, v0.x); v0.y = fmaf(a01.x, w2[4].y, v0.y);
    v0.x = fmaf(a01.y, w2[5].x, v0.x); v0.y = fmaf(a01.y, w2[5].y, v0.y);
    v0.x = fmaf(a01.z, w2[6].x, v0.x); v0.y = fmaf(a01.z, w2[6].y, v0.y);
    v0.x = fmaf(a01.w, w2[7].x, v0.x); v0.y = fmaf(a01.w, w2[7].y, v0.y);
    v1.x = g1.x + e1.x + bm.x; v1.y = g1.y + e1.y + bm.y;
    v1.x = fmaf(a10.x, w2[0].x, v1.x); v1.y = fmaf(a10.x, w2[0].y, v1.y);
    v1.x = fmaf(a10.y, w2[1].x, v1.x); v1.y = fmaf(a10.y, w2[1].y, v1.y);
    v1.x = fmaf(a10.z, w2[2].x, v1.x); v1.y = fmaf(a10.z, w2[2].y, v1.y);
    v1.x = fmaf(a10.w, w2[3].x, v1.x); v1.y = fmaf(a10.w, w2[3].y, v1.y);
    v1.x = fmaf(a11.x, w2[4].x, v1.x); v1.y = fmaf(a11.x, w2[4].y, v1.y);
    v1.x = fmaf(a11.y, w2[5].x, v1.x); v1.y = fmaf(a11.y, w2[5].y, v1.y);
    v1.x = fmaf(a11.z, w2[6].x, v1.x); v1.y = fmaf(a11.z, w2[6].y, v1.y);
    v1.x = fmaf(a11.w, w2[7].x, v1.x); v1.y = fmaf(a11.w, w2[7].y, v1.y);
    v2.x = g2.x + e2.x + bm.x; v2.y = g2.y + e2.y + bm.y;
    v2.x = fmaf(a20.x, w2[0].x, v2.x); v2.y = fmaf(a20.x, w2[0].y, v2.y);
    v2.x = fmaf(a20.y, w2[1].x, v2.x); v2.y = fmaf(a20.y, w2[1].y, v2.y);
    v2.x = fmaf(a20.z, w2[2].x, v2.x); v2.y = fmaf(a20.z, w2[2].y, v2.y);
    v2.x = fmaf(a20.w, w2[3].x, v2.x); v2.y = fmaf(a20.w, w2[3].y, v2.y);
    v2.x = fmaf(a21.x, w2[4].x, v2.x); v2.y = fmaf(a21.x, w2[4].y, v2.y);
    v2.x = fmaf(a21.y, w2[5].x, v2.x); v2.y = fmaf(a21.y, w2[5].y, v2.y);
    v2.x = fmaf(a21.z, w2[6].x, v2.x); v2.y = fmaf(a21.z, w2[6].y, v2.y);
    v2.x = fmaf(a21.w, w2[7].x, v2.x); v2.y = fmaf(a21.w, w2[7].y, v2.y);
    v3.x = g3.x + e3.x + bm.x; v3.y = g3.y + e3.y + bm.y;
    v3.x = fmaf(a30.x, w2[0].x, v3.x); v3.y = fmaf(a30.x, w2[0].y, v3.y);
    v3.x = fmaf(a30.y, w2[1].x, v3.x); v3.y = fmaf(a30.y, w2[1].y, v3.y);
    v3.x = fmaf(a30.z, w2[2].x, v3.x); v3.y = fmaf(a30.z, w2[2].y, v3.y);
    v3.x = fmaf(a30.w, w2[3].x, v3.x); v3.y = fmaf(a30.w, w2[3].y, v3.y);
    v3.x = fmaf(a31.x, w2[4].x, v3.x); v3.y = fmaf(a31.x, w2[4].y, v3.y);
    v3.x = fmaf(a31.y, w2[5].x, v3.x); v3.y = fmaf(a31.y, w2[5].y, v3.y);
    v3.x = fmaf(a31.z, w2[6].x, v3.x); v3.y = fmaf(a31.z, w2[6].y, v3.y);
    v3.x = fmaf(a31.w, w2[7].x, v3.x); v3.y = fmaf(a31.w, w2[7].y, v3.y);
    acc0.x += fmaxf(v0.x, 0.f); acc0.y += fmaxf(v0.y, 0.f);
    acc1.x += fmaxf(v1.x, 0.f); acc1.y += fmaxf(v1.y, 0.f);
    acc2.x += fmaxf(v2.x, 0.f); acc2.y += fmaxf(v2.y, 0.f);
    acc3.x += fmaxf(v3.x, 0.f); acc3.y += fmaxf(v3.y, 0.f);
  }
  for (; idx < end; idx++) {
    int p = epack[idx];
    int s = p & 0xFFFFF, t = p >> 20;
    float2 g = *(const float2*)&hW[(size_t)s * 64 + d0];
    float2 e = *(const float2*)&geW_l[t * 64 + d0];
    const float4* ep = (const float4*)(eap + (size_t)idx * 8);
    float4 a0 = ep[0], a1 = ep[1];
    float2 v;
    v.x = g.x + e.x + bm.x; v.y = g.y + e.y + bm.y;
    v.x = fmaf(a0.x, w2[0].x, v.x); v.y = fmaf(a0.x, w2[0].y, v.y);
    v.x = fmaf(a0.y, w2[1].x, v.x); v.y = fmaf(a0.y, w2[1].y, v.y);
    v.x = fmaf(a0.z, w2[2].x, v.x); v.y = fmaf(a0.z, w2[2].y, v.y);
    v.x = fmaf(a0.w, w2[3].x, v.x); v.y = fmaf(a0.w, w2[3].y, v.y);
    v.x = fmaf(a1.x, w2[4].x, v.x); v.y = fmaf(a1.x, w2[4].y, v.y);
    v.x = fmaf(a1.y, w2[5].x, v.x); v.y = fmaf(a1.y, w2[5].y, v.y);
    v.x = fmaf(a1.z, w2[6].x, v.x); v.y = fmaf(a1.z, w2[6].y, v.y);
    v.x = fmaf(a1.w, w2[7].x, v.x); v.y = fmaf(a1.w, w2[7].y, v.y);
    acc0.x += fmaxf(v.x, 0.f); acc0.y += fmaxf(v.y, 0.f);
  }
  float2 o;
  o.x = (acc0.x + acc1.x) + (acc2.x + acc3.x);
  o.y = (acc0.y + acc1.y) + (acc2.y + acc3.y);
  *(float2*)&agg[(size_t)n * 64 + d0] = o;
}

// -------- fused update + next-layer hW --------
__global__ __launch_bounds__(256) void update_fused_kernel(const float* __restrict__ h,
                                                           const float* __restrict__ agg,
                                                           const float* __restrict__ Wu,
                                                           const float* __restrict__ bu,
                                                           const float* __restrict__ W1next,
                                                           float* __restrict__ h_out,
                                                           float* __restrict__ hW_out,
                                                           int n_nodes) {
  __shared__ float As[128 * 64];
  int tid = threadIdx.x;
  int n0 = blockIdx.x * 64;
#pragma unroll
  for (int i = 0; i < 8; i++) {
    int flat = (tid + i * 256) * 4;
    int r = flat >> 7, k = flat & 127;
    float4 f = make_float4(0.f, 0.f, 0.f, 0.f);
    int n = n0 + r;
    if (n < n_nodes) {
      const float* sp = (k < 64) ? (h + (size_t)n * 64 + k) : (agg + (size_t)n * 64 + (k - 64));
      f = *(const float4*)sp;
    }
    int rp = r ^ (((k >> 2) & 7) << 2);
    As[(k + 0) * 64 + rp] = f.x;
    As[(k + 1) * 64 + rp] = f.y;
    As[(k + 2) * 64 + rp] = f.z;
    As[(k + 3) * 64 + rp] = f.w;
  }
  __syncthreads();
  int tx = tid & 15, ty = tid >> 4;
  float acc[4][4] = {{0.f}};
  const float4* WuV = (const float4*)Wu;
#pragma unroll 4
  for (int k = 0; k < 128; k++) {
    float4 a = *(const float4*)&As[k * 64 + ((ty * 4) ^ (((k >> 2) & 7) << 2))];
    float4 bb = WuV[k * 16 + tx];
    float av[4] = {a.x, a.y, a.z, a.w};
    float bv[4] = {bb.x, bb.y, bb.z, bb.w};
#pragma unroll
    for (int i = 0; i < 4; i++)
#pragma unroll
      for (int j = 0; j < 4; j++) acc[i][j] = fmaf(av[i], bv[j], acc[i][j]);
  }
  float hnew[4][4];
  float4 bv4 = *(const float4*)&bu[tx * 4];
#pragma unroll
  for (int i = 0; i < 4; i++) {
    int n = n0 + ty * 4 + i;
    if (n < n_nodes) {
      float4 hv = *(const float4*)&h[(size_t)n * 64 + tx * 4];
      hnew[i][0] = hv.x + acc[i][0] + bv4.x;
      hnew[i][1] = hv.y + acc[i][1] + bv4.y;
      hnew[i][2] = hv.z + acc[i][2] + bv4.z;
      hnew[i][3] = hv.w + acc[i][3] + bv4.w;
      float4 o = make_float4(hnew[i][0], hnew[i][1], hnew[i][2], hnew[i][3]);
      *(float4*)&h_out[(size_t)n * 64 + tx * 4] = o;
    } else {
      hnew[i][0] = hnew[i][1] = hnew[i][2] = hnew[i][3] = 0.f;
    }
  }
  if (W1next) {
    __syncthreads();
#pragma unroll
    for (int i = 0; i < 4; i++) {
      float4 o = make_float4(hnew[i][0], hnew[i][1], hnew[i][2], hnew[i][3]);
      *(float4*)&As[(ty * 4 + i) * 68 + tx * 4] = o;
    }
    __syncthreads();
    float acc2[4][4] = {{0.f}};
    const float4* W1V = (const float4*)W1next;
#pragma unroll 4
    for (int k = 0; k < 64; k++) {
      float av[4];
#pragma unroll
      for (int i = 0; i < 4; i++) av[i] = As[(ty * 4 + i) * 68 + k];
      float4 bb = W1V[k * 16 + tx];
      float bv[4] = {bb.x, bb.y, bb.z, bb.w};
#pragma unroll
      for (int i = 0; i < 4; i++)
#pragma unroll
        for (int j = 0; j < 4; j++) acc2[i][j] = fmaf(av[i], bv[j], acc2[i][j]);
    }
#pragma unroll
    for (int i = 0; i < 4; i++) {
      int n = n0 + ty * 4 + i;
      if (n < n_nodes) {
        float4 o = make_float4(acc2[i][0], acc2[i][1], acc2[i][2], acc2[i][3]);
        *(float4*)&hW_out[(size_t)n * 64 + tx * 4] = o;
      }
    }
  }
}

// ------- pooling stage 1: B*PSPLIT blocks, each reduces 1/PSPLIT of a graph -------
#define PSPLIT 8
__global__ __launch_bounds__(256) void pool_partial(const float* __restrict__ h,
                                                    const int* __restrict__ batch,
                                                    float* __restrict__ partials, int n_nodes) {
  int b = blockIdx.x / PSPLIT;
  int p = blockIdx.x % PSPLIT;
  int tid = threadIdx.x;
  int lane = tid & 63, wave = tid >> 6;
  __shared__ int se[2];
  if (tid < 2) se[tid] = lower_bound_dev(batch, n_nodes, b + tid);
  __syncthreads();
  int start = se[0], len = se[1] - se[0];
  int c0 = start + (int)(((long long)p * len) / PSPLIT);
  int c1 = start + (int)(((long long)(p + 1) * len) / PSPLIT);
  float s = 0.f, m = -INFINITY;
  for (int i = c0 + wave; i < c1; i += 4) {
    float v = h[(size_t)i * 64 + lane];
    s += v;
    m = fmaxf(m, v);
  }
  __shared__ float ss[4][64], mm[4][64];
  ss[wave][lane] = s;
  mm[wave][lane] = m;
  __syncthreads();
  if (wave == 0) {
    float sum = ss[0][lane] + ss[1][lane] + ss[2][lane] + ss[3][lane];
    float mx = fmaxf(fmaxf(mm[0][lane], mm[1][lane]), fmaxf(mm[2][lane], mm[3][lane]));
    float* dst = partials + ((size_t)(b * PSPLIT + p) * 2) * 64;
    dst[lane] = sum;
    dst[64 + lane] = mx;
  }
}

// ------- pooling stage 2 + head MLP (one block per graph) -------
__global__ __launch_bounds__(256) void pool_mlp_final(
    const float* __restrict__ partials, const int* __restrict__ batch,
    const float* __restrict__ glob,
    const float* __restrict__ W_gproj, const float* __restrict__ b_gproj,
    const float* __restrict__ g_gln, const float* __restrict__ b_gln,
    const float* __restrict__ W_c1, const float* __restrict__ b_c1,
    const float* __restrict__ g_cln, const float* __restrict__ b_cln,
    const float* __restrict__ W_c2, const float* __restrict__ b_c2,
    const float* __restrict__ W_head, const float* __restrict__ b_head,
    float* __restrict__ out, int n_nodes) {
  int b = blockIdx.x;
  int tid = threadIdx.x;
  int lane = tid & 63, wave = tid >> 6;
  __shared__ int se[2];
  if (tid < 2) se[tid] = lower_bound_dev(batch, n_nodes, b + tid);
  __shared__ float c[256];
  __shared__ float c1s[128];
  __shared__ float c2s[64];
  __shared__ float sred[2][2];
  __syncthreads();
  int cnt = se[1] - se[0];
  if (wave == 0) {
    const float* pp = partials + ((size_t)b * PSPLIT * 2) * 64;
    float sum = 0.f, mx = -INFINITY;
#pragma unroll
    for (int p = 0; p < PSPLIT; p++) {
      sum += pp[(size_t)p * 128 + lane];
      mx = fmaxf(mx, pp[(size_t)p * 128 + 64 + lane]);
    }
    float mean = (cnt > 0) ? sum / (float)cnt : 0.f;
    if (cnt == 0) { mx = 0.f; sum = 0.f; }
    c[lane] = mean;
    c[64 + lane] = mx;
    c[128 + lane] = sum;
  } else if (wave == 1) {
    const float* gf = glob + (size_t)b * 32;
    float acc = b_gproj[lane];
#pragma unroll
    for (int k = 0; k < 32; k++) acc = fmaf(gf[k], W_gproj[(size_t)k * 64 + lane], acc);
    acc = fmaxf(acc, 0.f);
    float sg = acc;
    for (int o = 32; o; o >>= 1) sg += __shfl_xor(sg, o);
    float mu = sg * (1.f / 64.f);
    float d = acc - mu;
    float vv = d * d;
    for (int o = 32; o; o >>= 1) vv += __shfl_xor(vv, o);
    float r = rsqrtf(vv * (1.f / 64.f) + 1e-5f);
    c[192 + lane] = d * r * g_gln[lane] + b_gln[lane];
  }
  __syncthreads();
  float acc1v = 0.f;
  if (tid < 128) {
    acc1v = b_c1[tid];
    for (int k = 0; k < 256; k++) acc1v = fmaf(c[k], W_c1[(size_t)k * 128 + tid], acc1v);
    acc1v = fmaxf(acc1v, 0.f);
    float srd = acc1v;
    for (int o = 32; o; o >>= 1) srd += __shfl_xor(srd, o);
    if (lane == 0) sred[0][wave] = srd;
  }
  __syncthreads();
  float mu = (sred[0][0] + sred[0][1]) * (1.f / 128.f);
  float d1 = 0.f;
  if (tid < 128) {
    d1 = acc1v - mu;
    float vv = d1 * d1;
    for (int o = 32; o; o >>= 1) vv += __shfl_xor(vv, o);
    if (lane == 0) sred[1][wave] = vv;
  }
  __syncthreads();
  float var = (sred[1][0] + sred[1][1]) * (1.f / 128.f);
  if (tid < 128) c1s[tid] = d1 * rsqrtf(var + 1e-5f) * g_cln[tid] + b_cln[tid];
  __syncthreads();
  if (tid < 64) {
    float a2 = b_c2[tid];
    for (int k = 0; k < 128; k++) a2 = fmaf(c1s[k], W_c2[(size_t)k * 64 + tid], a2);
    c2s[tid] = fmaxf(a2, 0.f);
  }
  __syncthreads();
  if (tid < 9) {
    float a3 = b_head[tid];
#pragma unroll
    for (int k = 0; k < 64; k++) a3 = fmaf(c2s[k], W_head[(size_t)k * 9 + tid], a3);
    out[(size_t)b * 9 + tid] = a3;
  }
}

extern "C" void kernel_launch(void* const* d_in, const int* in_sizes, int n_in,
                              void* d_out, int out_size, void* d_ws, size_t ws_size,
                              hipStream_t stream) {
  const float* x       = (const float*)d_in[0];
  const int* edge_index= (const int*)d_in[1];
  const float* edge_attr=(const float*)d_in[2];
  const int* gtype     = (const int*)d_in[3];
  const int* batch     = (const int*)d_in[4];
  const float* glob    = (const float*)d_in[5];
  const float* W_embed = (const float*)d_in[6];
  const float* b_embed = (const float*)d_in[7];
  const float* g_eln   = (const float*)d_in[8];
  const float* b_eln   = (const float*)d_in[9];
  const float* gate_emb= (const float*)d_in[10];
  const float* W_msg   = (const float*)d_in[11];
  const float* b_msg   = (const float*)d_in[12];
  const float* W_upd   = (const float*)d_in[13];
  const float* b_upd   = (const float*)d_in[14];
  const float* W_gproj = (const float*)d_in[15];
  const float* b_gproj = (const float*)d_in[16];
  const float* g_gln   = (const float*)d_in[17];
  const float* b_gln   = (const float*)d_in[18];
  const float* W_c1    = (const float*)d_in[19];
  const float* b_c1    = (const float*)d_in[20];
  const float* g_cln   = (const float*)d_in[21];
  const float* b_cln   = (const float*)d_in[22];
  const float* W_c2    = (const float*)d_in[23];
  const float* b_c2    = (const float*)d_in[24];
  const float* W_head  = (const float*)d_in[25];
  const float* b_head  = (const float*)d_in[26];

  const int N = in_sizes[0] / 16;
  const int E = in_sizes[1] / 2;
  const int B = in_sizes[5] / 32;
  const int L = in_sizes[12] / 64;

  const int* src = edge_index;
  const int* dst = edge_index + E;

  char* ws = (char*)d_ws;
  size_t off = 0;
  auto alloc = [&](size_t bytes) -> void* {
    void* p = ws + off;
    off += (bytes + 255) & ~(size_t)255;
    return p;
  };
  float* h      = (float*)alloc((size_t)N * 64 * 4);
  float* hW     = (float*)alloc((size_t)N * 64 * 4);
  float* agg    = (float*)alloc((size_t)N * 64 * 4);
  float* geW    = (float*)alloc((size_t)L * 20 * 64 * 4);
  float* partials = (float*)alloc((size_t)B * PSPLIT * 2 * 64 * 4);
  int nC4 = (N + 3) / 4;
  int* counts   = (int*)alloc((size_t)nC4 * 16);
  int* row_ptr  = (int*)alloc((size_t)(N + 1) * 4);
  int* nextp    = (int*)alloc((size_t)N * 4);
  int nb = (N + 1023) / 1024;
  int* blocksums= (int*)alloc((size_t)nb * 4);
  int* perm     = (int*)alloc((size_t)E * 4);
  int* epack0   = (int*)alloc((size_t)E * 4);
  int* epack    = (int*)alloc((size_t)E * 4);
  float* eap    = (float*)alloc((size_t)E * 8 * 4);

  zero_kernel<<<(nC4 + 255) / 256, 256, 0, stream>>>((int4*)counts, nC4);
  count_pack_kernel<<<(E + 255) / 256, 256, 0, stream>>>(dst, src, gtype, counts, epack0, E);
  scan_phase1<<<nb, 256, 0, stream>>>(counts, row_ptr, blocksums, N);
  scan_phase2<<<1, 64, 0, stream>>>(blocksums, nb);
  scan_phase3<<<(N + 255) / 256, 256, 0, stream>>>(row_ptr, blocksums, nextp, N, E);
  {
    int nchunks = (E + SP_EDGES_PER_BLOCK - 1) / SP_EDGES_PER_BLOCK;
    scatter_perm_binned<<<nchunks * 8, 256, 0, stream>>>(dst, nextp, perm, E, N);
  }
  gather_build<<<(E + 255) / 256, 256, 0, stream>>>(perm, epack0, edge_attr, epack, eap, E);
  gew_kernel<<<(L * 20 + 3) / 4, 256, 0, stream>>>(gate_emb, W_msg, geW, L * 20);
  embed_kernel<<<(N + 3) / 4, 256, 0, stream>>>(x, W_embed, b_embed, g_eln, b_eln, h, N);

  nodelin_kernel<<<(N + 63) / 64, 256, 0, stream>>>(h, W_msg, hW, N);
  for (int l = 0; l < L; l++) {
    edge_kernel<<<(N + 7) / 8, 256, 0, stream>>>(hW, epack, eap, row_ptr,
                                                 W_msg + (size_t)l * 88 * 64, b_msg + (size_t)l * 64,
                                                 geW + (size_t)l * 20 * 64, agg, N);
    const float* W1next = (l + 1 < L) ? (W_msg + (size_t)(l + 1) * 88 * 64) : nullptr;
    update_fused_kernel<<<(N + 63) / 64, 256, 0, stream>>>(h, agg, W_upd + (size_t)l * 128 * 64,
                                                           b_upd + (size_t)l * 64, W1next, h, hW, N);
  }

  pool_partial<<<B * PSPLIT, 256, 0, stream>>>(h, batch, partials, N);
  pool_mlp_final<<<B, 256, 0, stream>>>(partials, batch, glob, W_gproj, b_gproj, g_gln, b_gln,
                                        W_c1, b_c1, g_cln, b_cln, W_c2, b_c2,
                                        W_head, b_head, (float*)d_out, N);
}

// Round 13
// 487.234 us; speedup vs baseline: 1.1844x; 1.1844x over previous
//
#include <hip/hip_runtime.h>

__device__ __forceinline__ int rfl(int v) { return __builtin_amdgcn_readfirstlane(v); }

__device__ __forceinline__ int lower_bound_dev(const int* __restrict__ a, int n, int v) {
  int lo = 0, hi = n;
  while (lo < hi) { int mid = (lo + hi) >> 1; if (a[mid] < v) lo = mid + 1; else hi = mid; }
  return lo;
}

// ---------------- fast zero ----------------
__global__ void zero_kernel(int4* __restrict__ p, int n4) {
  int i = blockIdx.x * 256 + threadIdx.x;
  if (i < n4) p[i] = make_int4(0, 0, 0, 0);
}

// ---------------- CSR build ----------------
__global__ void count_pack_kernel(const int* __restrict__ dst, const int* __restrict__ src,
                                  const int* __restrict__ gt, int* __restrict__ counts,
                                  int* __restrict__ epack0, int E) {
  int e = blockIdx.x * 256 + threadIdx.x;
  if (e < E) {
    atomicAdd(&counts[dst[e]], 1);
    epack0[e] = (gt[e] << 20) | src[e];
  }
}

__global__ __launch_bounds__(256) void scan_phase1(const int* __restrict__ counts,
                                                   int* __restrict__ row_ptr,
                                                   int* __restrict__ blocksums, int n) {
  int tid = threadIdx.x;
  int i0 = blockIdx.x * 1024 + tid * 4;
  int4 c = make_int4(0, 0, 0, 0);
  if (i0 + 3 < n) {
    c = *(const int4*)(counts + i0);
  } else {
    if (i0 + 0 < n) c.x = counts[i0 + 0];
    if (i0 + 1 < n) c.y = counts[i0 + 1];
    if (i0 + 2 < n) c.z = counts[i0 + 2];
    if (i0 + 3 < n) c.w = counts[i0 + 3];
  }
  int s = c.x + c.y + c.z + c.w;
  int lane = tid & 63, wave = tid >> 6;
  int v = s;
  for (int o = 1; o < 64; o <<= 1) { int u = __shfl_up(v, o); if (lane >= o) v += u; }
  __shared__ int wsum[4];
  if (lane == 63) wsum[wave] = v;
  __syncthreads();
  int woff = 0;
  for (int w = 0; w < wave; w++) woff += wsum[w];
  int excl = woff + (v - s);
  if (tid == 255) blocksums[blockIdx.x] = woff + v;
  int p0 = excl, p1 = p0 + c.x, p2 = p1 + c.y, p3 = p2 + c.z;
  if (i0 + 3 < n) {
    *(int4*)(row_ptr + i0) = make_int4(p0, p1, p2, p3);
  } else {
    if (i0 + 0 < n) row_ptr[i0 + 0] = p0;
    if (i0 + 1 < n) row_ptr[i0 + 1] = p1;
    if (i0 + 2 < n) row_ptr[i0 + 2] = p2;
    if (i0 + 3 < n) row_ptr[i0 + 3] = p3;
  }
}

__global__ __launch_bounds__(64) void scan_phase2(int* __restrict__ blocksums, int nb) {
  int carry = 0;
  for (int base = 0; base < nb; base += 64) {
    int i = base + (int)threadIdx.x;
    int v = (i < nb) ? blocksums[i] : 0;
    int inc = v;
    for (int o = 1; o < 64; o <<= 1) { int u = __shfl_up(inc, o); if ((int)threadIdx.x >= o) inc += u; }
    if (i < nb) blocksums[i] = carry + inc - v;
    carry += __shfl(inc, 63);
  }
}

__global__ __launch_bounds__(256) void scan_phase3(int* __restrict__ row_ptr,
                                                   const int* __restrict__ blocksums,
                                                   int* __restrict__ nextp, int n, int E) {
  int i = blockIdx.x * 256 + threadIdx.x;
  if (i < n) {
    int v = row_ptr[i] + blocksums[i >> 10];
    row_ptr[i] = v;
    nextp[i] = v;
  }
  if (i == 0) row_ptr[n] = E;
}

// ---- bucket pass A: one sequential dst read; LDS histogram -> 8 dst-range buckets ----
__global__ __launch_bounds__(256) void bucket_kernel(const int* __restrict__ dst,
                                                     int* __restrict__ bcount,
                                                     int2* __restrict__ buckets,
                                                     int E, int n_nodes, int capb) {
  __shared__ int lcount[8];
  __shared__ int lbase[8];
  int tid = threadIdx.x;
  if (tid < 8) lcount[tid] = 0;
  __syncthreads();
  int e = blockIdx.x * 256 + tid;
  int b = 0, d = 0, slot = 0;
  bool ok = (e < E);
  if (ok) {
    d = dst[e];
    b = (int)(((long long)d * 8) / n_nodes);
    slot = atomicAdd(&lcount[b], 1);
  }
  __syncthreads();
  if (tid < 8) lbase[tid] = atomicAdd(&bcount[tid], lcount[tid]);
  __syncthreads();
  if (ok) {
    int pos = lbase[b] + slot;
    if (pos < capb) buckets[(size_t)b * capb + pos] = make_int2(e, d);
  }
}

// ---- bucket pass B: blockIdx&7 -> bucket (XCD-local nextp/perm); sequential entry reads ----
__global__ __launch_bounds__(256) void scatter_from_buckets(const int2* __restrict__ buckets,
                                                            const int* __restrict__ bcount,
                                                            int* __restrict__ nextp,
                                                            int* __restrict__ perm,
                                                            int capb) {
  int b = blockIdx.x & 7;
  int chunk = blockIdx.x >> 3;
  int cnt = bcount[b];
  if (cnt > capb) cnt = capb;
  int i0 = chunk * 1024 + threadIdx.x * 4;
  if (i0 >= cnt) return;
  const int4* bp = (const int4*)(buckets + (size_t)b * capb);
  int4 q0 = bp[i0 >> 1];
  int4 q1 = bp[(i0 >> 1) + 1];
  // entries: (q0.x,q0.y) (q0.z,q0.w) (q1.x,q1.y) (q1.z,q1.w)
  {
    int p = atomicAdd(&nextp[q0.y], 1); perm[p] = q0.x;
  }
  if (i0 + 1 < cnt) { int p = atomicAdd(&nextp[q0.w], 1); perm[p] = q0.z; }
  if (i0 + 2 < cnt) { int p = atomicAdd(&nextp[q1.y], 1); perm[p] = q1.x; }
  if (i0 + 3 < cnt) { int p = atomicAdd(&nextp[q1.w], 1); perm[p] = q1.z; }
}

// pass C: CSR-order gather; all writes sequential/coalesced.
__global__ void gather_build(const int* __restrict__ perm, const int* __restrict__ epack0,
                             const float* __restrict__ edge_attr,
                             int* __restrict__ epack, float* __restrict__ eap, int E) {
  int idx = blockIdx.x * 256 + threadIdx.x;
  if (idx < E) {
    int e = perm[idx];
    epack[idx] = epack0[e];
    const float4* s = (const float4*)(edge_attr + (size_t)e * 8);
    float4 a0 = s[0], a1 = s[1];
    float4* d = (float4*)(eap + (size_t)idx * 8);
    d[0] = a0; d[1] = a1;
  }
}

// ---------------- gate-embedding @ W3 table ----------------
__global__ void gew_kernel(const float* __restrict__ gate_emb, const float* __restrict__ W_msg,
                           float* __restrict__ geW, int nrows) {
  int tid = threadIdx.x;
  int lane = tid & 63;
  int row = blockIdx.x * 4 + (tid >> 6);
  if (row >= nrows) return;
  int l = row / 20, t = row % 20;
  const float* ge = gate_emb + ((size_t)l * 20 + t) * 16;
  const float* W3 = W_msg + (size_t)l * 88 * 64 + 72 * 64;
  float acc = 0.f;
#pragma unroll
  for (int k = 0; k < 16; k++) acc = fmaf(ge[k], W3[(size_t)k * 64 + lane], acc);
  geW[(size_t)row * 64 + lane] = acc;
}

// ---------------- node embed ----------------
__global__ __launch_bounds__(256) void embed_kernel(const float* __restrict__ x,
                                                    const float* __restrict__ W,
                                                    const float* __restrict__ b,
                                                    const float* __restrict__ gamma,
                                                    const float* __restrict__ beta,
                                                    float* __restrict__ h, int n_nodes) {
  __shared__ float Ws[16 * 64];
  int tid = threadIdx.x;
  for (int i = tid; i < 16 * 64; i += 256) Ws[i] = W[i];
  __syncthreads();
  int lane = tid & 63;
  int n = blockIdx.x * 4 + (tid >> 6);
  if (n >= n_nodes) return;
  const float* xr = x + (size_t)n * 16;
  float acc = b[lane];
#pragma unroll
  for (int k = 0; k < 16; k++) acc = fmaf(xr[k], Ws[k * 64 + lane], acc);
  acc = fmaxf(acc, 0.f);
  float s = acc;
  for (int o = 32; o; o >>= 1) s += __shfl_xor(s, o);
  float mu = s * (1.f / 64.f);
  float d = acc - mu;
  float v = d * d;
  for (int o = 32; o; o >>= 1) v += __shfl_xor(v, o);
  float r = rsqrtf(v * (1.f / 64.f) + 1e-5f);
  h[(size_t)n * 64 + lane] = d * r * gamma[lane] + beta[lane];
}

// ---- tiled GEMM: C = A @ W (layer-0 hW); swizzled A tile, W from L1 ----
__global__ __launch_bounds__(256) void nodelin_kernel(const float* __restrict__ A,
                                                      const float* __restrict__ W,
                                                      float* __restrict__ C, int n_nodes) {
  __shared__ float As[64 * 64];
  int tid = threadIdx.x;
  int n0 = blockIdx.x * 64;
#pragma unroll
  for (int i = 0; i < 4; i++) {
    int flat = (tid + i * 256) * 4;
    int r = flat >> 6, k = flat & 63;
    float4 f = make_float4(0.f, 0.f, 0.f, 0.f);
    int n = n0 + r;
    if (n < n_nodes) f = *(const float4*)(A + (size_t)n * 64 + k);
    int rp = r ^ (((k >> 2) & 7) << 2);
    As[(k + 0) * 64 + rp] = f.x;
    As[(k + 1) * 64 + rp] = f.y;
    As[(k + 2) * 64 + rp] = f.z;
    As[(k + 3) * 64 + rp] = f.w;
  }
  __syncthreads();
  int tx = tid & 15, ty = tid >> 4;
  float acc[4][4] = {{0.f}};
  const float4* WV = (const float4*)W;
#pragma unroll 4
  for (int k = 0; k < 64; k++) {
    float4 a = *(const float4*)&As[k * 64 + ((ty * 4) ^ (((k >> 2) & 7) << 2))];
    float4 bb = WV[k * 16 + tx];
    float av[4] = {a.x, a.y, a.z, a.w};
    float bv[4] = {bb.x, bb.y, bb.z, bb.w};
#pragma unroll
    for (int i = 0; i < 4; i++)
#pragma unroll
      for (int j = 0; j < 4; j++) acc[i][j] = fmaf(av[i], bv[j], acc[i][j]);
  }
#pragma unroll
  for (int i = 0; i < 4; i++) {
    int n = n0 + ty * 4 + i;
    if (n < n_nodes) {
      float4 o = make_float4(acc[i][0], acc[i][1], acc[i][2], acc[i][3]);
      *(float4*)&C[(size_t)n * 64 + tx * 4] = o;
    }
  }
}

// -------- edge stage (R9 config: ILP-4, wave-uniform scalar loop) --------
__global__ __launch_bounds__(256, 4) void edge_kernel(const float* __restrict__ hW,
                                                      const int* __restrict__ epack,
                                                      const float* __restrict__ eap,
                                                      const int* __restrict__ row_ptr,
                                                      const float* __restrict__ W_msg_l,
                                                      const float* __restrict__ b_msg_l,
                                                      const float* __restrict__ geW_l,
                                                      float* __restrict__ agg, int n_nodes) {
  int tid = threadIdx.x;
  int lane = tid & 63;
  int n = blockIdx.x * 4 + (tid >> 6);
  if (n >= n_nodes) return;
  float w2[8];
#pragma unroll
  for (int k = 0; k < 8; k++) w2[k] = W_msg_l[(size_t)(64 + k) * 64 + lane];
  float bm = b_msg_l[lane];
  int beg = rfl(row_ptr[n]);
  int end = rfl(row_ptr[n + 1]);
  float acc0 = 0.f, acc1 = 0.f, acc2 = 0.f, acc3 = 0.f;
  int idx = beg;
  for (; idx + 4 <= end; idx += 4) {
    int p0 = rfl(epack[idx + 0]);
    int p1 = rfl(epack[idx + 1]);
    int p2 = rfl(epack[idx + 2]);
    int p3 = rfl(epack[idx + 3]);
    int s0 = p0 & 0xFFFFF, t0 = p0 >> 20;
    int s1 = p1 & 0xFFFFF, t1 = p1 >> 20;
    int s2 = p2 & 0xFFFFF, t2 = p2 >> 20;
    int s3 = p3 & 0xFFFFF, t3 = p3 >> 20;
    float g0 = hW[(size_t)s0 * 64 + lane];
    float g1 = hW[(size_t)s1 * 64 + lane];
    float g2 = hW[(size_t)s2 * 64 + lane];
    float g3 = hW[(size_t)s3 * 64 + lane];
    float e0 = geW_l[t0 * 64 + lane];
    float e1 = geW_l[t1 * 64 + lane];
    float e2 = geW_l[t2 * 64 + lane];
    float e3 = geW_l[t3 * 64 + lane];
    const float4* ep = (const float4*)(eap + (size_t)idx * 8);
    float4 a00 = ep[0], a01 = ep[1], a10 = ep[2], a11 = ep[3];
    float4 a20 = ep[4], a21 = ep[5], a30 = ep[6], a31 = ep[7];
    float v0 = g0 + e0 + bm;
    v0 = fmaf(a00.x, w2[0], v0); v0 = fmaf(a00.y, w2[1], v0);
    v0 = fmaf(a00.z, w2[2], v0); v0 = fmaf(a00.w, w2[3], v0);
    v0 = fmaf(a01.x, w2[4], v0); v0 = fmaf(a01.y, w2[5], v0);
    v0 = fmaf(a01.z, w2[6], v0); v0 = fmaf(a01.w, w2[7], v0);
    float v1 = g1 + e1 + bm;
    v1 = fmaf(a10.x, w2[0], v1); v1 = fmaf(a10.y, w2[1], v1);
    v1 = fmaf(a10.z, w2[2], v1); v1 = fmaf(a10.w, w2[3], v1);
    v1 = fmaf(a11.x, w2[4], v1); v1 = fmaf(a11.y, w2[5], v1);
    v1 = fmaf(a11.z, w2[6], v1); v1 = fmaf(a11.w, w2[7], v1);
    float v2 = g2 + e2 + bm;
    v2 = fmaf(a20.x, w2[0], v2); v2 = fmaf(a20.y, w2[1], v2);
    v2 = fmaf(a20.z, w2[2], v2); v2 = fmaf(a20.w, w2[3], v2);
    v2 = fmaf(a21.x, w2[4], v2); v2 = fmaf(a21.y, w2[5], v2);
    v2 = fmaf(a21.z, w2[6], v2); v2 = fmaf(a21.w, w2[7], v2);
    float v3 = g3 + e3 + bm;
    v3 = fmaf(a30.x, w2[0], v3); v3 = fmaf(a30.y, w2[1], v3);
    v3 = fmaf(a30.z, w2[2], v3); v3 = fmaf(a30.w, w2[3], v3);
    v3 = fmaf(a31.x, w2[4], v3); v3 = fmaf(a31.y, w2[5], v3);
    v3 = fmaf(a31.z, w2[6], v3); v3 = fmaf(a31.w, w2[7], v3);
    acc0 += fmaxf(v0, 0.f);
    acc1 += fmaxf(v1, 0.f);
    acc2 += fmaxf(v2, 0.f);
    acc3 += fmaxf(v3, 0.f);
  }
  for (; idx < end; idx++) {
    int p = rfl(epack[idx]);
    int s = p & 0xFFFFF, t = p >> 20;
    const float4* ep = (const float4*)(eap + (size_t)idx * 8);
    float4 a0 = ep[0], a1 = ep[1];
    float g = hW[(size_t)s * 64 + lane];
    float v = g + geW_l[t * 64 + lane] + bm;
    v = fmaf(a0.x, w2[0], v); v = fmaf(a0.y, w2[1], v);
    v = fmaf(a0.z, w2[2], v); v = fmaf(a0.w, w2[3], v);
    v = fmaf(a1.x, w2[4], v); v = fmaf(a1.y, w2[5], v);
    v = fmaf(a1.z, w2[6], v); v = fmaf(a1.w, w2[7], v);
    acc0 += fmaxf(v, 0.f);
  }
  agg[(size_t)n * 64 + lane] = (acc0 + acc1) + (acc2 + acc3);
}

// -------- fused update + next-layer hW --------
__global__ __launch_bounds__(256) void update_fused_kernel(const float* __restrict__ h,
                                                           const float* __restrict__ agg,
                                                           const float* __restrict__ Wu,
                                                           const float* __restrict__ bu,
                                                           const float* __restrict__ W1next,
                                                           float* __restrict__ h_out,
                                                           float* __restrict__ hW_out,
                                                           int n_nodes) {
  __shared__ float As[128 * 64];
  int tid = threadIdx.x;
  int n0 = blockIdx.x * 64;
#pragma unroll
  for (int i = 0; i < 8; i++) {
    int flat = (tid + i * 256) * 4;
    int r = flat >> 7, k = flat & 127;
    float4 f = make_float4(0.f, 0.f, 0.f, 0.f);
    int n = n0 + r;
    if (n < n_nodes) {
      const float* sp = (k < 64) ? (h + (size_t)n * 64 + k) : (agg + (size_t)n * 64 + (k - 64));
      f = *(const float4*)sp;
    }
    int rp = r ^ (((k >> 2) & 7) << 2);
    As[(k + 0) * 64 + rp] = f.x;
    As[(k + 1) * 64 + rp] = f.y;
    As[(k + 2) * 64 + rp] = f.z;
    As[(k + 3) * 64 + rp] = f.w;
  }
  __syncthreads();
  int tx = tid & 15, ty = tid >> 4;
  float acc[4][4] = {{0.f}};
  const float4* WuV = (const float4*)Wu;
#pragma unroll 4
  for (int k = 0; k < 128; k++) {
    float4 a = *(const float4*)&As[k * 64 + ((ty * 4) ^ (((k >> 2) & 7) << 2))];
    float4 bb = WuV[k * 16 + tx];
    float av[4] = {a.x, a.y, a.z, a.w};
    float bv[4] = {bb.x, bb.y, bb.z, bb.w};
#pragma unroll
    for (int i = 0; i < 4; i++)
#pragma unroll
      for (int j = 0; j < 4; j++) acc[i][j] = fmaf(av[i], bv[j], acc[i][j]);
  }
  float hnew[4][4];
  float4 bv4 = *(const float4*)&bu[tx * 4];
#pragma unroll
  for (int i = 0; i < 4; i++) {
    int n = n0 + ty * 4 + i;
    if (n < n_nodes) {
      float4 hv = *(const float4*)&h[(size_t)n * 64 + tx * 4];
      hnew[i][0] = hv.x + acc[i][0] + bv4.x;
      hnew[i][1] = hv.y + acc[i][1] + bv4.y;
      hnew[i][2] = hv.z + acc[i][2] + bv4.z;
      hnew[i][3] = hv.w + acc[i][3] + bv4.w;
      float4 o = make_float4(hnew[i][0], hnew[i][1], hnew[i][2], hnew[i][3]);
      *(float4*)&h_out[(size_t)n * 64 + tx * 4] = o;
    } else {
      hnew[i][0] = hnew[i][1] = hnew[i][2] = hnew[i][3] = 0.f;
    }
  }
  if (W1next) {
    __syncthreads();
#pragma unroll
    for (int i = 0; i < 4; i++) {
      float4 o = make_float4(hnew[i][0], hnew[i][1], hnew[i][2], hnew[i][3]);
      *(float4*)&As[(ty * 4 + i) * 68 + tx * 4] = o;
    }
    __syncthreads();
    float acc2[4][4] = {{0.f}};
    const float4* W1V = (const float4*)W1next;
#pragma unroll 4
    for (int k = 0; k < 64; k++) {
      float av[4];
#pragma unroll
      for (int i = 0; i < 4; i++) av[i] = As[(ty * 4 + i) * 68 + k];
      float4 bb = W1V[k * 16 + tx];
      float bv[4] = {bb.x, bb.y, bb.z, bb.w};
#pragma unroll
      for (int i = 0; i < 4; i++)
#pragma unroll
        for (int j = 0; j < 4; j++) acc2[i][j] = fmaf(av[i], bv[j], acc2[i][j]);
    }
#pragma unroll
    for (int i = 0; i < 4; i++) {
      int n = n0 + ty * 4 + i;
      if (n < n_nodes) {
        float4 o = make_float4(acc2[i][0], acc2[i][1], acc2[i][2], acc2[i][3]);
        *(float4*)&hW_out[(size_t)n * 64 + tx * 4] = o;
      }
    }
  }
}

// ------- pooling stage 1: B*PSPLIT blocks, each reduces 1/PSPLIT of a graph -------
#define PSPLIT 8
__global__ __launch_bounds__(256) void pool_partial(const float* __restrict__ h,
                                                    const int* __restrict__ batch,
                                                    float* __restrict__ partials, int n_nodes) {
  int b = blockIdx.x / PSPLIT;
  int p = blockIdx.x % PSPLIT;
  int tid = threadIdx.x;
  int lane = tid & 63, wave = tid >> 6;
  __shared__ int se[2];
  if (tid < 2) se[tid] = lower_bound_dev(batch, n_nodes, b + tid);
  __syncthreads();
  int start = se[0], len = se[1] - se[0];
  int c0 = start + (int)(((long long)p * len) / PSPLIT);
  int c1 = start + (int)(((long long)(p + 1) * len) / PSPLIT);
  float s = 0.f, m = -INFINITY;
  for (int i = c0 + wave; i < c1; i += 4) {
    float v = h[(size_t)i * 64 + lane];
    s += v;
    m = fmaxf(m, v);
  }
  __shared__ float ss[4][64], mm[4][64];
  ss[wave][lane] = s;
  mm[wave][lane] = m;
  __syncthreads();
  if (wave == 0) {
    float sum = ss[0][lane] + ss[1][lane] + ss[2][lane] + ss[3][lane];
    float mx = fmaxf(fmaxf(mm[0][lane], mm[1][lane]), fmaxf(mm[2][lane], mm[3][lane]));
    float* dst = partials + ((size_t)(b * PSPLIT + p) * 2) * 64;
    dst[lane] = sum;
    dst[64 + lane] = mx;
  }
}

// ------- pooling stage 2 + head MLP (one block per graph) -------
__global__ __launch_bounds__(256) void pool_mlp_final(
    const float* __restrict__ partials, const int* __restrict__ batch,
    const float* __restrict__ glob,
    const float* __restrict__ W_gproj, const float* __restrict__ b_gproj,
    const float* __restrict__ g_gln, const float* __restrict__ b_gln,
    const float* __restrict__ W_c1, const float* __restrict__ b_c1,
    const float* __restrict__ g_cln, const float* __restrict__ b_cln,
    const float* __restrict__ W_c2, const float* __restrict__ b_c2,
    const float* __restrict__ W_head, const float* __restrict__ b_head,
    float* __restrict__ out, int n_nodes) {
  int b = blockIdx.x;
  int tid = threadIdx.x;
  int lane = tid & 63, wave = tid >> 6;
  __shared__ int se[2];
  if (tid < 2) se[tid] = lower_bound_dev(batch, n_nodes, b + tid);
  __shared__ float c[256];
  __shared__ float c1s[128];
  __shared__ float c2s[64];
  __shared__ float sred[2][2];
  __syncthreads();
  int cnt = se[1] - se[0];
  if (wave == 0) {
    const float* pp = partials + ((size_t)b * PSPLIT * 2) * 64;
    float sum = 0.f, mx = -INFINITY;
#pragma unroll
    for (int p = 0; p < PSPLIT; p++) {
      sum += pp[(size_t)p * 128 + lane];
      mx = fmaxf(mx, pp[(size_t)p * 128 + 64 + lane]);
    }
    float mean = (cnt > 0) ? sum / (float)cnt : 0.f;
    if (cnt == 0) { mx = 0.f; sum = 0.f; }
    c[lane] = mean;
    c[64 + lane] = mx;
    c[128 + lane] = sum;
  } else if (wave == 1) {
    const float* gf = glob + (size_t)b * 32;
    float acc = b_gproj[lane];
#pragma unroll
    for (int k = 0; k < 32; k++) acc = fmaf(gf[k], W_gproj[(size_t)k * 64 + lane], acc);
    acc = fmaxf(acc, 0.f);
    float sg = acc;
    for (int o = 32; o; o >>= 1) sg += __shfl_xor(sg, o);
    float mu = sg * (1.f / 64.f);
    float d = acc - mu;
    float vv = d * d;
    for (int o = 32; o; o >>= 1) vv += __shfl_xor(vv, o);
    float r = rsqrtf(vv * (1.f / 64.f) + 1e-5f);
    c[192 + lane] = d * r * g_gln[lane] + b_gln[lane];
  }
  __syncthreads();
  float acc1v = 0.f;
  if (tid < 128) {
    acc1v = b_c1[tid];
    for (int k = 0; k < 256; k++) acc1v = fmaf(c[k], W_c1[(size_t)k * 128 + tid], acc1v);
    acc1v = fmaxf(acc1v, 0.f);
    float srd = acc1v;
    for (int o = 32; o; o >>= 1) srd += __shfl_xor(srd, o);
    if (lane == 0) sred[0][wave] = srd;
  }
  __syncthreads();
  float mu = (sred[0][0] + sred[0][1]) * (1.f / 128.f);
  float d1 = 0.f;
  if (tid < 128) {
    d1 = acc1v - mu;
    float vv = d1 * d1;
    for (int o = 32; o; o >>= 1) vv += __shfl_xor(vv, o);
    if (lane == 0) sred[1][wave] = vv;
  }
  __syncthreads();
  float var = (sred[1][0] + sred[1][1]) * (1.f / 128.f);
  if (tid < 128) c1s[tid] = d1 * rsqrtf(var + 1e-5f) * g_cln[tid] + b_cln[tid];
  __syncthreads();
  if (tid < 64) {
    float a2 = b_c2[tid];
    for (int k = 0; k < 128; k++) a2 = fmaf(c1s[k], W_c2[(size_t)k * 64 + tid], a2);
    c2s[tid] = fmaxf(a2, 0.f);
  }
  __syncthreads();
  if (tid < 9) {
    float a3 = b_head[tid];
#pragma unroll
    for (int k = 0; k < 64; k++) a3 = fmaf(c2s[k], W_head[(size_t)k * 9 + tid], a3);
    out[(size_t)b * 9 + tid] = a3;
  }
}

extern "C" void kernel_launch(void* const* d_in, const int* in_sizes, int n_in,
                              void* d_out, int out_size, void* d_ws, size_t ws_size,
                              hipStream_t stream) {
  const float* x       = (const float*)d_in[0];
  const int* edge_index= (const int*)d_in[1];
  const float* edge_attr=(const float*)d_in[2];
  const int* gtype     = (const int*)d_in[3];
  const int* batch     = (const int*)d_in[4];
  const float* glob    = (const float*)d_in[5];
  const float* W_embed = (const float*)d_in[6];
  const float* b_embed = (const float*)d_in[7];
  const float* g_eln   = (const float*)d_in[8];
  const float* b_eln   = (const float*)d_in[9];
  const float* gate_emb= (const float*)d_in[10];
  const float* W_msg   = (const float*)d_in[11];
  const float* b_msg   = (const float*)d_in[12];
  const float* W_upd   = (const float*)d_in[13];
  const float* b_upd   = (const float*)d_in[14];
  const float* W_gproj = (const float*)d_in[15];
  const float* b_gproj = (const float*)d_in[16];
  const float* g_gln   = (const float*)d_in[17];
  const float* b_gln   = (const float*)d_in[18];
  const float* W_c1    = (const float*)d_in[19];
  const float* b_c1    = (const float*)d_in[20];
  const float* g_cln   = (const float*)d_in[21];
  const float* b_cln   = (const float*)d_in[22];
  const float* W_c2    = (const float*)d_in[23];
  const float* b_c2    = (const float*)d_in[24];
  const float* W_head  = (const float*)d_in[25];
  const float* b_head  = (const float*)d_in[26];

  const int N = in_sizes[0] / 16;
  const int E = in_sizes[1] / 2;
  const int B = in_sizes[5] / 32;
  const int L = in_sizes[12] / 64;

  const int* src = edge_index;
  const int* dst = edge_index + E;

  char* ws = (char*)d_ws;
  size_t off = 0;
  auto alloc = [&](size_t bytes) -> void* {
    void* p = ws + off;
    off += (bytes + 255) & ~(size_t)255;
    return p;
  };
  float* h      = (float*)alloc((size_t)N * 64 * 4);
  float* hW     = (float*)alloc((size_t)N * 64 * 4);
  float* agg    = (float*)alloc((size_t)N * 64 * 4);
  float* geW    = (float*)alloc((size_t)L * 20 * 64 * 4);
  float* partials = (float*)alloc((size_t)B * PSPLIT * 2 * 64 * 4);
  int nC4 = (N + 3) / 4;
  // counts (+8 ints for bcount directly after, zeroed together)
  int* counts   = (int*)alloc((size_t)nC4 * 16 + 32);
  int* bcount   = counts + nC4 * 4;
  int* row_ptr  = (int*)alloc((size_t)(N + 1) * 4);
  int* nextp    = (int*)alloc((size_t)N * 4);
  int nb = (N + 1023) / 1024;
  int* blocksums= (int*)alloc((size_t)nb * 4);
  int* perm     = (int*)alloc((size_t)E * 4);
  int* epack0   = (int*)alloc((size_t)E * 4);
  int* epack    = (int*)alloc((size_t)E * 4);
  float* eap    = (float*)alloc((size_t)E * 8 * 4);
  int capb = E / 8 + E / 32 + 64;              // 8 dst-range buckets, ~50-sigma margin
  int2* buckets = (int2*)alloc((size_t)capb * 8 * 8);

  int nZ4 = nC4 + 2;  // counts + bcount
  zero_kernel<<<(nZ4 + 255) / 256, 256, 0, stream>>>((int4*)counts, nZ4);
  count_pack_kernel<<<(E + 255) / 256, 256, 0, stream>>>(dst, src, gtype, counts, epack0, E);
  scan_phase1<<<nb, 256, 0, stream>>>(counts, row_ptr, blocksums, N);
  scan_phase2<<<1, 64, 0, stream>>>(blocksums, nb);
  scan_phase3<<<(N + 255) / 256, 256, 0, stream>>>(row_ptr, blocksums, nextp, N, E);
  bucket_kernel<<<(E + 255) / 256, 256, 0, stream>>>(dst, bcount, buckets, E, N, capb);
  {
    int chunksB = (capb + 1023) / 1024;
    scatter_from_buckets<<<chunksB * 8, 256, 0, stream>>>(buckets, bcount, nextp, perm, capb);
  }
  gather_build<<<(E + 255) / 256, 256, 0, stream>>>(perm, epack0, edge_attr, epack, eap, E);
  gew_kernel<<<(L * 20 + 3) / 4, 256, 0, stream>>>(gate_emb, W_msg, geW, L * 20);
  embed_kernel<<<(N + 3) / 4, 256, 0, stream>>>(x, W_embed, b_embed, g_eln, b_eln, h, N);

  nodelin_kernel<<<(N + 63) / 64, 256, 0, stream>>>(h, W_msg, hW, N);
  for (int l = 0; l < L; l++) {
    edge_kernel<<<(N + 3) / 4, 256, 0, stream>>>(hW, epack, eap, row_ptr,
                                                 W_msg + (size_t)l * 88 * 64, b_msg + (size_t)l * 64,
                                                 geW + (size_t)l * 20 * 64, agg, N);
    const float* W1next = (l + 1 < L) ? (W_msg + (size_t)(l + 1) * 88 * 64) : nullptr;
    update_fused_kernel<<<(N + 63) / 64, 256, 0, stream>>>(h, agg, W_upd + (size_t)l * 128 * 64,
                                                           b_upd + (size_t)l * 64, W1next, h, hW, N);
  }

  pool_partial<<<B * PSPLIT, 256, 0, stream>>>(h, batch, partials, N);
  pool_mlp_final<<<B, 256, 0, stream>>>(partials, batch, glob, W_gproj, b_gproj, g_gln, b_gln,
                                        W_c1, b_c1, g_cln, b_cln, W_c2, b_c2,
                                        W_head, b_head, (float*)d_out, N);
}

// Round 14
// 445.937 us; speedup vs baseline: 1.2940x; 1.0926x over previous
//
#include <hip/hip_runtime.h>

__device__ __forceinline__ int rfl(int v) { return __builtin_amdgcn_readfirstlane(v); }

__device__ __forceinline__ int lower_bound_dev(const int* __restrict__ a, int n, int v) {
  int lo = 0, hi = n;
  while (lo < hi) { int mid = (lo + hi) >> 1; if (a[mid] < v) lo = mid + 1; else hi = mid; }
  return lo;
}

// ---------------- fast zero ----------------
__global__ void zero_kernel(int4* __restrict__ p, int n4) {
  int i = blockIdx.x * 256 + threadIdx.x;
  if (i < n4) p[i] = make_int4(0, 0, 0, 0);
}

// ---------------- CSR build ----------------
__global__ void count_pack_kernel(const int* __restrict__ dst, const int* __restrict__ src,
                                  const int* __restrict__ gt, int* __restrict__ counts,
                                  int* __restrict__ epack0, int E) {
  int e = blockIdx.x * 256 + threadIdx.x;
  if (e < E) {
    atomicAdd(&counts[dst[e]], 1);
    epack0[e] = (gt[e] << 20) | src[e];
  }
}

__global__ __launch_bounds__(256) void scan_phase1(const int* __restrict__ counts,
                                                   int* __restrict__ row_ptr,
                                                   int* __restrict__ blocksums, int n) {
  int tid = threadIdx.x;
  int i0 = blockIdx.x * 1024 + tid * 4;
  int4 c = make_int4(0, 0, 0, 0);
  if (i0 + 3 < n) {
    c = *(const int4*)(counts + i0);
  } else {
    if (i0 + 0 < n) c.x = counts[i0 + 0];
    if (i0 + 1 < n) c.y = counts[i0 + 1];
    if (i0 + 2 < n) c.z = counts[i0 + 2];
    if (i0 + 3 < n) c.w = counts[i0 + 3];
  }
  int s = c.x + c.y + c.z + c.w;
  int lane = tid & 63, wave = tid >> 6;
  int v = s;
  for (int o = 1; o < 64; o <<= 1) { int u = __shfl_up(v, o); if (lane >= o) v += u; }
  __shared__ int wsum[4];
  if (lane == 63) wsum[wave] = v;
  __syncthreads();
  int woff = 0;
  for (int w = 0; w < wave; w++) woff += wsum[w];
  int excl = woff + (v - s);
  if (tid == 255) blocksums[blockIdx.x] = woff + v;
  int p0 = excl, p1 = p0 + c.x, p2 = p1 + c.y, p3 = p2 + c.z;
  if (i0 + 3 < n) {
    *(int4*)(row_ptr + i0) = make_int4(p0, p1, p2, p3);
  } else {
    if (i0 + 0 < n) row_ptr[i0 + 0] = p0;
    if (i0 + 1 < n) row_ptr[i0 + 1] = p1;
    if (i0 + 2 < n) row_ptr[i0 + 2] = p2;
    if (i0 + 3 < n) row_ptr[i0 + 3] = p3;
  }
}

__global__ __launch_bounds__(64) void scan_phase2(int* __restrict__ blocksums, int nb) {
  int carry = 0;
  for (int base = 0; base < nb; base += 64) {
    int i = base + (int)threadIdx.x;
    int v = (i < nb) ? blocksums[i] : 0;
    int inc = v;
    for (int o = 1; o < 64; o <<= 1) { int u = __shfl_up(inc, o); if ((int)threadIdx.x >= o) inc += u; }
    if (i < nb) blocksums[i] = carry + inc - v;
    carry += __shfl(inc, 63);
  }
}

__global__ __launch_bounds__(256) void scan_phase3(int* __restrict__ row_ptr,
                                                   const int* __restrict__ blocksums,
                                                   int* __restrict__ nextp, int n, int E) {
  int i = blockIdx.x * 256 + threadIdx.x;
  if (i < n) {
    int v = row_ptr[i] + blocksums[i >> 10];
    row_ptr[i] = v;
    nextp[i] = v;
  }
  if (i == 0) row_ptr[n] = E;
}

// XCD-binned scatter (R9 config — measured 40us): 8 dst-range phases.
#define SP_EDGES_PER_BLOCK 2048
__global__ __launch_bounds__(256) void scatter_perm_binned(const int* __restrict__ dst,
                                                           int* __restrict__ nextp,
                                                           int* __restrict__ perm,
                                                           int E, int n_nodes) {
  int phase = blockIdx.x & 7;
  int chunk = blockIdx.x >> 3;
  int lo = (int)(((long long)phase * n_nodes) >> 3);
  int hi = (int)(((long long)(phase + 1) * n_nodes) >> 3);
  int base = chunk * SP_EDGES_PER_BLOCK + threadIdx.x * 8;
#pragma unroll
  for (int half = 0; half < 2; half++) {
    int b = base + half * 4;
    if (b >= E) break;
    int4 d;
    if (b + 3 < E) {
      d = *(const int4*)(dst + b);
    } else {
      d.x = dst[b];
      d.y = (b + 1 < E) ? dst[b + 1] : -1;
      d.z = (b + 2 < E) ? dst[b + 2] : -1;
      d.w = (b + 3 < E) ? dst[b + 3] : -1;
    }
    if (d.x >= lo && d.x < hi) { int p = atomicAdd(&nextp[d.x], 1); perm[p] = b + 0; }
    if (d.y >= lo && d.y < hi) { int p = atomicAdd(&nextp[d.y], 1); perm[p] = b + 1; }
    if (d.z >= lo && d.z < hi) { int p = atomicAdd(&nextp[d.z], 1); perm[p] = b + 2; }
    if (d.w >= lo && d.w < hi) { int p = atomicAdd(&nextp[d.w], 1); perm[p] = b + 3; }
  }
}

// pass B (R9 config): CSR-order gather; all writes sequential/coalesced.
__global__ void gather_build(const int* __restrict__ perm, const int* __restrict__ epack0,
                             const float* __restrict__ edge_attr,
                             int* __restrict__ epack, float* __restrict__ eap, int E) {
  int idx = blockIdx.x * 256 + threadIdx.x;
  if (idx < E) {
    int e = perm[idx];
    epack[idx] = epack0[e];
    const float4* s = (const float4*)(edge_attr + (size_t)e * 8);
    float4 a0 = s[0], a1 = s[1];
    float4* d = (float4*)(eap + (size_t)idx * 8);
    d[0] = a0; d[1] = a1;
  }
}

// ---------------- gate-embedding @ W3 table ----------------
__global__ void gew_kernel(const float* __restrict__ gate_emb, const float* __restrict__ W_msg,
                           float* __restrict__ geW, int nrows) {
  int tid = threadIdx.x;
  int lane = tid & 63;
  int row = blockIdx.x * 4 + (tid >> 6);
  if (row >= nrows) return;
  int l = row / 20, t = row % 20;
  const float* ge = gate_emb + ((size_t)l * 20 + t) * 16;
  const float* W3 = W_msg + (size_t)l * 88 * 64 + 72 * 64;
  float acc = 0.f;
#pragma unroll
  for (int k = 0; k < 16; k++) acc = fmaf(ge[k], W3[(size_t)k * 64 + lane], acc);
  geW[(size_t)row * 64 + lane] = acc;
}

// ---------------- node embed ----------------
__global__ __launch_bounds__(256) void embed_kernel(const float* __restrict__ x,
                                                    const float* __restrict__ W,
                                                    const float* __restrict__ b,
                                                    const float* __restrict__ gamma,
                                                    const float* __restrict__ beta,
                                                    float* __restrict__ h, int n_nodes) {
  __shared__ float Ws[16 * 64];
  int tid = threadIdx.x;
  for (int i = tid; i < 16 * 64; i += 256) Ws[i] = W[i];
  __syncthreads();
  int lane = tid & 63;
  int n = blockIdx.x * 4 + (tid >> 6);
  if (n >= n_nodes) return;
  const float* xr = x + (size_t)n * 16;
  float acc = b[lane];
#pragma unroll
  for (int k = 0; k < 16; k++) acc = fmaf(xr[k], Ws[k * 64 + lane], acc);
  acc = fmaxf(acc, 0.f);
  float s = acc;
  for (int o = 32; o; o >>= 1) s += __shfl_xor(s, o);
  float mu = s * (1.f / 64.f);
  float d = acc - mu;
  float v = d * d;
  for (int o = 32; o; o >>= 1) v += __shfl_xor(v, o);
  float r = rsqrtf(v * (1.f / 64.f) + 1e-5f);
  h[(size_t)n * 64 + lane] = d * r * gamma[lane] + beta[lane];
}

// ---- tiled GEMM: C = A @ W (layer-0 hW); swizzled A tile, W from L1 ----
__global__ __launch_bounds__(256) void nodelin_kernel(const float* __restrict__ A,
                                                      const float* __restrict__ W,
                                                      float* __restrict__ C, int n_nodes) {
  __shared__ float As[64 * 64];
  int tid = threadIdx.x;
  int n0 = blockIdx.x * 64;
#pragma unroll
  for (int i = 0; i < 4; i++) {
    int flat = (tid + i * 256) * 4;
    int r = flat >> 6, k = flat & 63;
    float4 f = make_float4(0.f, 0.f, 0.f, 0.f);
    int n = n0 + r;
    if (n < n_nodes) f = *(const float4*)(A + (size_t)n * 64 + k);
    int rp = r ^ (((k >> 2) & 7) << 2);
    As[(k + 0) * 64 + rp] = f.x;
    As[(k + 1) * 64 + rp] = f.y;
    As[(k + 2) * 64 + rp] = f.z;
    As[(k + 3) * 64 + rp] = f.w;
  }
  __syncthreads();
  int tx = tid & 15, ty = tid >> 4;
  float acc[4][4] = {{0.f}};
  const float4* WV = (const float4*)W;
#pragma unroll 4
  for (int k = 0; k < 64; k++) {
    float4 a = *(const float4*)&As[k * 64 + ((ty * 4) ^ (((k >> 2) & 7) << 2))];
    float4 bb = WV[k * 16 + tx];
    float av[4] = {a.x, a.y, a.z, a.w};
    float bv[4] = {bb.x, bb.y, bb.z, bb.w};
#pragma unroll
    for (int i = 0; i < 4; i++)
#pragma unroll
      for (int j = 0; j < 4; j++) acc[i][j] = fmaf(av[i], bv[j], acc[i][j]);
  }
#pragma unroll
  for (int i = 0; i < 4; i++) {
    int n = n0 + ty * 4 + i;
    if (n < n_nodes) {
      float4 o = make_float4(acc[i][0], acc[i][1], acc[i][2], acc[i][3]);
      *(float4*)&C[(size_t)n * 64 + tx * 4] = o;
    }
  }
}

// -------- edge stage (R9 config: ILP-4, wave-uniform scalar loop) --------
__global__ __launch_bounds__(256, 4) void edge_kernel(const float* __restrict__ hW,
                                                      const int* __restrict__ epack,
                                                      const float* __restrict__ eap,
                                                      const int* __restrict__ row_ptr,
                                                      const float* __restrict__ W_msg_l,
                                                      const float* __restrict__ b_msg_l,
                                                      const float* __restrict__ geW_l,
                                                      float* __restrict__ agg, int n_nodes) {
  int tid = threadIdx.x;
  int lane = tid & 63;
  int n = blockIdx.x * 4 + (tid >> 6);
  if (n >= n_nodes) return;
  float w2[8];
#pragma unroll
  for (int k = 0; k < 8; k++) w2[k] = W_msg_l[(size_t)(64 + k) * 64 + lane];
  float bm = b_msg_l[lane];
  int beg = rfl(row_ptr[n]);
  int end = rfl(row_ptr[n + 1]);
  float acc0 = 0.f, acc1 = 0.f, acc2 = 0.f, acc3 = 0.f;
  int idx = beg;
  for (; idx + 4 <= end; idx += 4) {
    int p0 = rfl(epack[idx + 0]);
    int p1 = rfl(epack[idx + 1]);
    int p2 = rfl(epack[idx + 2]);
    int p3 = rfl(epack[idx + 3]);
    int s0 = p0 & 0xFFFFF, t0 = p0 >> 20;
    int s1 = p1 & 0xFFFFF, t1 = p1 >> 20;
    int s2 = p2 & 0xFFFFF, t2 = p2 >> 20;
    int s3 = p3 & 0xFFFFF, t3 = p3 >> 20;
    float g0 = hW[(size_t)s0 * 64 + lane];
    float g1 = hW[(size_t)s1 * 64 + lane];
    float g2 = hW[(size_t)s2 * 64 + lane];
    float g3 = hW[(size_t)s3 * 64 + lane];
    float e0 = geW_l[t0 * 64 + lane];
    float e1 = geW_l[t1 * 64 + lane];
    float e2 = geW_l[t2 * 64 + lane];
    float e3 = geW_l[t3 * 64 + lane];
    const float4* ep = (const float4*)(eap + (size_t)idx * 8);
    float4 a00 = ep[0], a01 = ep[1], a10 = ep[2], a11 = ep[3];
    float4 a20 = ep[4], a21 = ep[5], a30 = ep[6], a31 = ep[7];
    float v0 = g0 + e0 + bm;
    v0 = fmaf(a00.x, w2[0], v0); v0 = fmaf(a00.y, w2[1], v0);
    v0 = fmaf(a00.z, w2[2], v0); v0 = fmaf(a00.w, w2[3], v0);
    v0 = fmaf(a01.x, w2[4], v0); v0 = fmaf(a01.y, w2[5], v0);
    v0 = fmaf(a01.z, w2[6], v0); v0 = fmaf(a01.w, w2[7], v0);
    float v1 = g1 + e1 + bm;
    v1 = fmaf(a10.x, w2[0], v1); v1 = fmaf(a10.y, w2[1], v1);
    v1 = fmaf(a10.z, w2[2], v1); v1 = fmaf(a10.w, w2[3], v1);
    v1 = fmaf(a11.x, w2[4], v1); v1 = fmaf(a11.y, w2[5], v1);
    v1 = fmaf(a11.z, w2[6], v1); v1 = fmaf(a11.w, w2[7], v1);
    float v2 = g2 + e2 + bm;
    v2 = fmaf(a20.x, w2[0], v2); v2 = fmaf(a20.y, w2[1], v2);
    v2 = fmaf(a20.z, w2[2], v2); v2 = fmaf(a20.w, w2[3], v2);
    v2 = fmaf(a21.x, w2[4], v2); v2 = fmaf(a21.y, w2[5], v2);
    v2 = fmaf(a21.z, w2[6], v2); v2 = fmaf(a21.w, w2[7], v2);
    float v3 = g3 + e3 + bm;
    v3 = fmaf(a30.x, w2[0], v3); v3 = fmaf(a30.y, w2[1], v3);
    v3 = fmaf(a30.z, w2[2], v3); v3 = fmaf(a30.w, w2[3], v3);
    v3 = fmaf(a31.x, w2[4], v3); v3 = fmaf(a31.y, w2[5], v3);
    v3 = fmaf(a31.z, w2[6], v3); v3 = fmaf(a31.w, w2[7], v3);
    acc0 += fmaxf(v0, 0.f);
    acc1 += fmaxf(v1, 0.f);
    acc2 += fmaxf(v2, 0.f);
    acc3 += fmaxf(v3, 0.f);
  }
  for (; idx < end; idx++) {
    int p = rfl(epack[idx]);
    int s = p & 0xFFFFF, t = p >> 20;
    const float4* ep = (const float4*)(eap + (size_t)idx * 8);
    float4 a0 = ep[0], a1 = ep[1];
    float g = hW[(size_t)s * 64 + lane];
    float v = g + geW_l[t * 64 + lane] + bm;
    v = fmaf(a0.x, w2[0], v); v = fmaf(a0.y, w2[1], v);
    v = fmaf(a0.z, w2[2], v); v = fmaf(a0.w, w2[3], v);
    v = fmaf(a1.x, w2[4], v); v = fmaf(a1.y, w2[5], v);
    v = fmaf(a1.z, w2[6], v); v = fmaf(a1.w, w2[7], v);
    acc0 += fmaxf(v, 0.f);
  }
  agg[(size_t)n * 64 + lane] = (acc0 + acc1) + (acc2 + acc3);
}

// -------- fused update + next-layer hW --------
__global__ __launch_bounds__(256) void update_fused_kernel(const float* __restrict__ h,
                                                           const float* __restrict__ agg,
                                                           const float* __restrict__ Wu,
                                                           const float* __restrict__ bu,
                                                           const float* __restrict__ W1next,
                                                           float* __restrict__ h_out,
                                                           float* __restrict__ hW_out,
                                                           int n_nodes) {
  __shared__ float As[128 * 64];
  int tid = threadIdx.x;
  int n0 = blockIdx.x * 64;
#pragma unroll
  for (int i = 0; i < 8; i++) {
    int flat = (tid + i * 256) * 4;
    int r = flat >> 7, k = flat & 127;
    float4 f = make_float4(0.f, 0.f, 0.f, 0.f);
    int n = n0 + r;
    if (n < n_nodes) {
      const float* sp = (k < 64) ? (h + (size_t)n * 64 + k) : (agg + (size_t)n * 64 + (k - 64));
      f = *(const float4*)sp;
    }
    int rp = r ^ (((k >> 2) & 7) << 2);
    As[(k + 0) * 64 + rp] = f.x;
    As[(k + 1) * 64 + rp] = f.y;
    As[(k + 2) * 64 + rp] = f.z;
    As[(k + 3) * 64 + rp] = f.w;
  }
  __syncthreads();
  int tx = tid & 15, ty = tid >> 4;
  float acc[4][4] = {{0.f}};
  const float4* WuV = (const float4*)Wu;
#pragma unroll 4
  for (int k = 0; k < 128; k++) {
    float4 a = *(const float4*)&As[k * 64 + ((ty * 4) ^ (((k >> 2) & 7) << 2))];
    float4 bb = WuV[k * 16 + tx];
    float av[4] = {a.x, a.y, a.z, a.w};
    float bv[4] = {bb.x, bb.y, bb.z, bb.w};
#pragma unroll
    for (int i = 0; i < 4; i++)
#pragma unroll
      for (int j = 0; j < 4; j++) acc[i][j] = fmaf(av[i], bv[j], acc[i][j]);
  }
  float hnew[4][4];
  float4 bv4 = *(const float4*)&bu[tx * 4];
#pragma unroll
  for (int i = 0; i < 4; i++) {
    int n = n0 + ty * 4 + i;
    if (n < n_nodes) {
      float4 hv = *(const float4*)&h[(size_t)n * 64 + tx * 4];
      hnew[i][0] = hv.x + acc[i][0] + bv4.x;
      hnew[i][1] = hv.y + acc[i][1] + bv4.y;
      hnew[i][2] = hv.z + acc[i][2] + bv4.z;
      hnew[i][3] = hv.w + acc[i][3] + bv4.w;
      float4 o = make_float4(hnew[i][0], hnew[i][1], hnew[i][2], hnew[i][3]);
      *(float4*)&h_out[(size_t)n * 64 + tx * 4] = o;
    } else {
      hnew[i][0] = hnew[i][1] = hnew[i][2] = hnew[i][3] = 0.f;
    }
  }
  if (W1next) {
    __syncthreads();
#pragma unroll
    for (int i = 0; i < 4; i++) {
      float4 o = make_float4(hnew[i][0], hnew[i][1], hnew[i][2], hnew[i][3]);
      *(float4*)&As[(ty * 4 + i) * 68 + tx * 4] = o;
    }
    __syncthreads();
    float acc2[4][4] = {{0.f}};
    const float4* W1V = (const float4*)W1next;
#pragma unroll 4
    for (int k = 0; k < 64; k++) {
      float av[4];
#pragma unroll
      for (int i = 0; i < 4; i++) av[i] = As[(ty * 4 + i) * 68 + k];
      float4 bb = W1V[k * 16 + tx];
      float bv[4] = {bb.x, bb.y, bb.z, bb.w};
#pragma unroll
      for (int i = 0; i < 4; i++)
#pragma unroll
        for (int j = 0; j < 4; j++) acc2[i][j] = fmaf(av[i], bv[j], acc2[i][j]);
    }
#pragma unroll
    for (int i = 0; i < 4; i++) {
      int n = n0 + ty * 4 + i;
      if (n < n_nodes) {
        float4 o = make_float4(acc2[i][0], acc2[i][1], acc2[i][2], acc2[i][3]);
        *(float4*)&hW_out[(size_t)n * 64 + tx * 4] = o;
      }
    }
  }
}

// ------- pooling stage 1: B*PSPLIT blocks, each reduces 1/PSPLIT of a graph -------
#define PSPLIT 8
__global__ __launch_bounds__(256) void pool_partial(const float* __restrict__ h,
                                                    const int* __restrict__ batch,
                                                    float* __restrict__ partials, int n_nodes) {
  int b = blockIdx.x / PSPLIT;
  int p = blockIdx.x % PSPLIT;
  int tid = threadIdx.x;
  int lane = tid & 63, wave = tid >> 6;
  __shared__ int se[2];
  if (tid < 2) se[tid] = lower_bound_dev(batch, n_nodes, b + tid);
  __syncthreads();
  int start = se[0], len = se[1] - se[0];
  int c0 = start + (int)(((long long)p * len) / PSPLIT);
  int c1 = start + (int)(((long long)(p + 1) * len) / PSPLIT);
  float s = 0.f, m = -INFINITY;
  for (int i = c0 + wave; i < c1; i += 4) {
    float v = h[(size_t)i * 64 + lane];
    s += v;
    m = fmaxf(m, v);
  }
  __shared__ float ss[4][64], mm[4][64];
  ss[wave][lane] = s;
  mm[wave][lane] = m;
  __syncthreads();
  if (wave == 0) {
    float sum = ss[0][lane] + ss[1][lane] + ss[2][lane] + ss[3][lane];
    float mx = fmaxf(fmaxf(mm[0][lane], mm[1][lane]), fmaxf(mm[2][lane], mm[3][lane]));
    float* dst = partials + ((size_t)(b * PSPLIT + p) * 2) * 64;
    dst[lane] = sum;
    dst[64 + lane] = mx;
  }
}

// ------- pooling stage 2 + head MLP (one block per graph) -------
__global__ __launch_bounds__(256) void pool_mlp_final(
    const float* __restrict__ partials, const int* __restrict__ batch,
    const float* __restrict__ glob,
    const float* __restrict__ W_gproj, const float* __restrict__ b_gproj,
    const float* __restrict__ g_gln, const float* __restrict__ b_gln,
    const float* __restrict__ W_c1, const float* __restrict__ b_c1,
    const float* __restrict__ g_cln, const float* __restrict__ b_cln,
    const float* __restrict__ W_c2, const float* __restrict__ b_c2,
    const float* __restrict__ W_head, const float* __restrict__ b_head,
    float* __restrict__ out, int n_nodes) {
  int b = blockIdx.x;
  int tid = threadIdx.x;
  int lane = tid & 63, wave = tid >> 6;
  __shared__ int se[2];
  if (tid < 2) se[tid] = lower_bound_dev(batch, n_nodes, b + tid);
  __shared__ float c[256];
  __shared__ float c1s[128];
  __shared__ float c2s[64];
  __shared__ float sred[2][2];
  __syncthreads();
  int cnt = se[1] - se[0];
  if (wave == 0) {
    const float* pp = partials + ((size_t)b * PSPLIT * 2) * 64;
    float sum = 0.f, mx = -INFINITY;
#pragma unroll
    for (int p = 0; p < PSPLIT; p++) {
      sum += pp[(size_t)p * 128 + lane];
      mx = fmaxf(mx, pp[(size_t)p * 128 + 64 + lane]);
    }
    float mean = (cnt > 0) ? sum / (float)cnt : 0.f;
    if (cnt == 0) { mx = 0.f; sum = 0.f; }
    c[lane] = mean;
    c[64 + lane] = mx;
    c[128 + lane] = sum;
  } else if (wave == 1) {
    const float* gf = glob + (size_t)b * 32;
    float acc = b_gproj[lane];
#pragma unroll
    for (int k = 0; k < 32; k++) acc = fmaf(gf[k], W_gproj[(size_t)k * 64 + lane], acc);
    acc = fmaxf(acc, 0.f);
    float sg = acc;
    for (int o = 32; o; o >>= 1) sg += __shfl_xor(sg, o);
    float mu = sg * (1.f / 64.f);
    float d = acc - mu;
    float vv = d * d;
    for (int o = 32; o; o >>= 1) vv += __shfl_xor(vv, o);
    float r = rsqrtf(vv * (1.f / 64.f) + 1e-5f);
    c[192 + lane] = d * r * g_gln[lane] + b_gln[lane];
  }
  __syncthreads();
  float acc1v = 0.f;
  if (tid < 128) {
    acc1v = b_c1[tid];
    for (int k = 0; k < 256; k++) acc1v = fmaf(c[k], W_c1[(size_t)k * 128 + tid], acc1v);
    acc1v = fmaxf(acc1v, 0.f);
    float srd = acc1v;
    for (int o = 32; o; o >>= 1) srd += __shfl_xor(srd, o);
    if (lane == 0) sred[0][wave] = srd;
  }
  __syncthreads();
  float mu = (sred[0][0] + sred[0][1]) * (1.f / 128.f);
  float d1 = 0.f;
  if (tid < 128) {
    d1 = acc1v - mu;
    float vv = d1 * d1;
    for (int o = 32; o; o >>= 1) vv += __shfl_xor(vv, o);
    if (lane == 0) sred[1][wave] = vv;
  }
  __syncthreads();
  float var = (sred[1][0] + sred[1][1]) * (1.f / 128.f);
  if (tid < 128) c1s[tid] = d1 * rsqrtf(var + 1e-5f) * g_cln[tid] + b_cln[tid];
  __syncthreads();
  if (tid < 64) {
    float a2 = b_c2[tid];
    for (int k = 0; k < 128; k++) a2 = fmaf(c1s[k], W_c2[(size_t)k * 64 + tid], a2);
    c2s[tid] = fmaxf(a2, 0.f);
  }
  __syncthreads();
  if (tid < 9) {
    float a3 = b_head[tid];
#pragma unroll
    for (int k = 0; k < 64; k++) a3 = fmaf(c2s[k], W_head[(size_t)k * 9 + tid], a3);
    out[(size_t)b * 9 + tid] = a3;
  }
}

extern "C" void kernel_launch(void* const* d_in, const int* in_sizes, int n_in,
                              void* d_out, int out_size, void* d_ws, size_t ws_size,
                              hipStream_t stream) {
  const float* x       = (const float*)d_in[0];
  const int* edge_index= (const int*)d_in[1];
  const float* edge_attr=(const float*)d_in[2];
  const int* gtype     = (const int*)d_in[3];
  const int* batch     = (const int*)d_in[4];
  const float* glob    = (const float*)d_in[5];
  const float* W_embed = (const float*)d_in[6];
  const float* b_embed = (const float*)d_in[7];
  const float* g_eln   = (const float*)d_in[8];
  const float* b_eln   = (const float*)d_in[9];
  const float* gate_emb= (const float*)d_in[10];
  const float* W_msg   = (const float*)d_in[11];
  const float* b_msg   = (const float*)d_in[12];
  const float* W_upd   = (const float*)d_in[13];
  const float* b_upd   = (const float*)d_in[14];
  const float* W_gproj = (const float*)d_in[15];
  const float* b_gproj = (const float*)d_in[16];
  const float* g_gln   = (const float*)d_in[17];
  const float* b_gln   = (const float*)d_in[18];
  const float* W_c1    = (const float*)d_in[19];
  const float* b_c1    = (const float*)d_in[20];
  const float* g_cln   = (const float*)d_in[21];
  const float* b_cln   = (const float*)d_in[22];
  const float* W_c2    = (const float*)d_in[23];
  const float* b_c2    = (const float*)d_in[24];
  const float* W_head  = (const float*)d_in[25];
  const float* b_head  = (const float*)d_in[26];

  const int N = in_sizes[0] / 16;
  const int E = in_sizes[1] / 2;
  const int B = in_sizes[5] / 32;
  const int L = in_sizes[12] / 64;

  const int* src = edge_index;
  const int* dst = edge_index + E;

  char* ws = (char*)d_ws;
  size_t off = 0;
  auto alloc = [&](size_t bytes) -> void* {
    void* p = ws + off;
    off += (bytes + 255) & ~(size_t)255;
    return p;
  };
  float* h      = (float*)alloc((size_t)N * 64 * 4);
  float* hW     = (float*)alloc((size_t)N * 64 * 4);
  float* agg    = (float*)alloc((size_t)N * 64 * 4);
  float* geW    = (float*)alloc((size_t)L * 20 * 64 * 4);
  float* partials = (float*)alloc((size_t)B * PSPLIT * 2 * 64 * 4);
  int nC4 = (N + 3) / 4;
  int* counts   = (int*)alloc((size_t)nC4 * 16);
  int* row_ptr  = (int*)alloc((size_t)(N + 1) * 4);
  int* nextp    = (int*)alloc((size_t)N * 4);
  int nb = (N + 1023) / 1024;
  int* blocksums= (int*)alloc((size_t)nb * 4);
  int* perm     = (int*)alloc((size_t)E * 4);
  int* epack0   = (int*)alloc((size_t)E * 4);
  int* epack    = (int*)alloc((size_t)E * 4);
  float* eap    = (float*)alloc((size_t)E * 8 * 4);

  zero_kernel<<<(nC4 + 255) / 256, 256, 0, stream>>>((int4*)counts, nC4);
  count_pack_kernel<<<(E + 255) / 256, 256, 0, stream>>>(dst, src, gtype, counts, epack0, E);
  scan_phase1<<<nb, 256, 0, stream>>>(counts, row_ptr, blocksums, N);
  scan_phase2<<<1, 64, 0, stream>>>(blocksums, nb);
  scan_phase3<<<(N + 255) / 256, 256, 0, stream>>>(row_ptr, blocksums, nextp, N, E);
  {
    int nchunks = (E + SP_EDGES_PER_BLOCK - 1) / SP_EDGES_PER_BLOCK;
    scatter_perm_binned<<<nchunks * 8, 256, 0, stream>>>(dst, nextp, perm, E, N);
  }
  gather_build<<<(E + 255) / 256, 256, 0, stream>>>(perm, epack0, edge_attr, epack, eap, E);
  gew_kernel<<<(L * 20 + 3) / 4, 256, 0, stream>>>(gate_emb, W_msg, geW, L * 20);
  embed_kernel<<<(N + 3) / 4, 256, 0, stream>>>(x, W_embed, b_embed, g_eln, b_eln, h, N);

  nodelin_kernel<<<(N + 63) / 64, 256, 0, stream>>>(h, W_msg, hW, N);
  for (int l = 0; l < L; l++) {
    edge_kernel<<<(N + 3) / 4, 256, 0, stream>>>(hW, epack, eap, row_ptr,
                                                 W_msg + (size_t)l * 88 * 64, b_msg + (size_t)l * 64,
                                                 geW + (size_t)l * 20 * 64, agg, N);
    const float* W1next = (l + 1 < L) ? (W_msg + (size_t)(l + 1) * 88 * 64) : nullptr;
    update_fused_kernel<<<(N + 63) / 64, 256, 0, stream>>>(h, agg, W_upd + (size_t)l * 128 * 64,
                                                           b_upd + (size_t)l * 64, W1next, h, hW, N);
  }

  pool_partial<<<B * PSPLIT, 256, 0, stream>>>(h, batch, partials, N);
  pool_mlp_final<<<B, 256, 0, stream>>>(partials, batch, glob, W_gproj, b_gproj, g_gln, b_gln,
                                        W_c1, b_c1, g_cln, b_cln, W_c2, b_c2,
                                        W_head, b_head, (float*)d_out, N);
}